// Round 17
// baseline (20.858 us; speedup 1.0000x reference)
//
#include <hip/hip_runtime.h>

#define BLOCK 256
#define EPSF 1e-8f

// 16-byte vector load with only 4-byte alignment guarantee (rows are 44 B).
typedef float f4u __attribute__((ext_vector_type(4), aligned(4)));

struct Row9 { f4u b0, b1, b2, t0, t1, t2, w0, w1, w2; };

__device__ __forceinline__ Row9 load_row(const float* __restrict__ box,
                                         const float* __restrict__ tgt,
                                         const float* __restrict__ wgt,
                                         size_t r) {
    Row9 R;
    R.b0 = *(const f4u*)(box + r); R.b1 = *(const f4u*)(box + r + 4); R.b2 = *(const f4u*)(box + r + 7);
    R.t0 = *(const f4u*)(tgt + r); R.t1 = *(const f4u*)(tgt + r + 4); R.t2 = *(const f4u*)(tgt + r + 7);
    R.w0 = *(const f4u*)(wgt + r); R.w1 = *(const f4u*)(wgt + r + 4); R.w2 = *(const f4u*)(wgt + r + 7);
    return R;
}

__device__ __forceinline__ float safe_rcp(float d) {
    float sd = (fabsf(d) > 1e-30f) ? d : copysignf(1e-30f, d);
    return __frcp_rn(sd);
}

// Clipped length of segment p + t*d, t in [0,1], vs |x|<=hx,|y|<=hy.
__device__ __forceinline__ float clip_len(float px, float py,
                                          float rdx, float rdy,
                                          float hx, float hy) {
    float t1x = (-hx - px) * rdx, t2x = (hx - px) * rdx;
    float t1y = (-hy - py) * rdy, t2y = (hy - py) * rdy;
    float tmin = fmaxf(fmaxf(fminf(t1x, t2x), fminf(t1y, t2y)), 0.f);
    float tmax = fminf(fminf(fmaxf(t1x, t2x), fmaxf(t1y, t2y)), 1.f);
    return fmaxf(tmax - tmin, 0.f);
}

__device__ __forceinline__ void box_compute(const Row9& R, float& l1out, float& gout)
{
    f4u b0 = R.b0, b1 = R.b1, b2 = R.b2;
    f4u t0 = R.t0, t1 = R.t1, t2 = R.t2;
    f4u w0 = R.w0, w1 = R.w1, w2 = R.w2;

    // ---- L1 loss over the 11 components ----
    float lb = 0.f;
    lb += fabsf(b0.x - t0.x) * w0.x;
    lb += fabsf(b0.y - t0.y) * w0.y;
    lb += fabsf(b0.z - t0.z) * w0.z;
    lb += fabsf(b0.w - t0.w) * w0.w;
    lb += fabsf(b1.x - t1.x) * w1.x;
    lb += fabsf(b1.y - t1.y) * w1.y;
    lb += fabsf(b1.z - t1.z) * w1.z;
    lb += fabsf(b1.w - t1.w) * w1.w;
    lb += fabsf(b2.y - t2.y) * w2.y;
    lb += fabsf(b2.z - t2.z) * w2.z;
    lb += fabsf(b2.w - t2.w) * w2.w;
    l1out = lb;

    // ---- decode: sin(atan2(s,c)) = s*rsqrt(s^2+c^2); exp via HW ----
    float cx1 = b0.x, cy1 = b0.y, cx2 = t0.x, cy2 = t0.y;
    float w1v = __expf(b0.w), l1v = __expf(b1.x);
    float w2v = __expf(t0.w), l2v = __expf(t1.x);
    float r1 = rsqrtf(fmaxf(b1.z * b1.z + b1.w * b1.w, 1e-30f));
    float s1 = b1.z * r1, c1 = b1.w * r1;
    float r2 = rsqrtf(fmaxf(t1.z * t1.z + t1.w * t1.w, 1e-30f));
    float s2 = t1.z * r2, c2 = t1.w * r2;

    float hx1 = 0.5f * w1v, hy1 = 0.5f * l1v;
    float hx2 = 0.5f * w2v, hy2 = 0.5f * l2v;

    // enclosing AABB (world frame), closed form
    float e1x = fabsf(hx1 * c1) + fabsf(hy1 * s1);
    float e1y = fabsf(hx1 * s1) + fabsf(hy1 * c1);
    float e2x = fabsf(hx2 * c2) + fabsf(hy2 * s2);
    float e2y = fabsf(hx2 * s2) + fabsf(hy2 * c2);
    float enc = (fmaxf(cx1 + e1x, cx2 + e2x) - fminf(cx1 - e1x, cx2 - e2x))
              * (fmaxf(cy1 + e1y, cy2 + e2y) - fminf(cy1 - e1y, cy2 - e2y));

    // rect1 pose in rect2's local frame (rect2 axis-aligned there)
    float dxw = cx1 - cx2, dyw = cy1 - cy2;
    float txl =  c2 * dxw + s2 * dyw;
    float tyl = -s2 * dxw + c2 * dyw;
    float cr_ = c1 * c2 + s1 * s2;     // cos(yaw1 - yaw2)
    float sr_ = s1 * c2 - c1 * s2;     // sin(yaw1 - yaw2)

    // rect1 corners in frame2 via shared products
    float ax_ = hx1 * cr_, ay_ = hx1 * sr_;
    float bx_ = hy1 * sr_, by_ = hy1 * cr_;
    float q0x = txl - ax_ + bx_, q0y = tyl - ay_ - by_;
    float q1x = txl + ax_ + bx_, q1y = tyl + ay_ - by_;
    float q2x = txl + ax_ - bx_, q2y = tyl + ay_ + by_;
    float q3x = txl - ax_ - bx_, q3y = tyl - ay_ + by_;

    // ---- Green's theorem: inter2 = sum over boundary segments of
    // (tb-ta)*cross(p,d), all crosses evaluated in frame2 ----
    float inter2 = 0.f;

    // Part 1: rect1 edges vs rect2's box; edges 2,3 antiparallel to 0,1.
    {
        float d01x = 2.f * ax_, d01y = 2.f * ay_;
        float d12x = -2.f * bx_, d12y = 2.f * by_;
        float r01x = safe_rcp(d01x), r01y = safe_rcp(d01y);
        float r12x = safe_rcp(d12x), r12y = safe_rcp(d12y);

        float L0 = clip_len(q0x, q0y,  r01x,  r01y, hx2, hy2);
        inter2 += L0 * (q0x * d01y - q0y * d01x);
        float L1 = clip_len(q1x, q1y,  r12x,  r12y, hx2, hy2);
        inter2 += L1 * (q1x * d12y - q1y * d12x);
        float L2 = clip_len(q2x, q2y, -r01x, -r01y, hx2, hy2);
        inter2 += L2 * (q2y * d01x - q2x * d01y);
        float L3 = clip_len(q3x, q3y, -r12x, -r12y, hx2, hy2);
        inter2 += L3 * (q3y * d12x - q3x * d12y);
    }

    // Part 2: rect2 edges vs rect1's box; cross(p,d) == 2*hx2*hy2.
    {
        float zx = -hx2 - txl, zy = -hy2 - tyl;
        float u0x =  cr_ * zx + sr_ * zy;
        float u0y = -sr_ * zx + cr_ * zy;
        float E0x =  2.f * hx2 * cr_, E0y = -2.f * hx2 * sr_;
        float E1x =  2.f * hy2 * sr_, E1y =  2.f * hy2 * cr_;
        float u1x = u0x + E0x, u1y = u0y + E0y;
        float u2x = u1x + E1x, u2y = u1y + E1y;
        float u3x = u0x + E1x, u3y = u0y + E1y;
        float re0x = safe_rcp(E0x), re0y = safe_rcp(E0y);
        float re1x = safe_rcp(E1x), re1y = safe_rcp(E1y);

        float tsum = 0.f;
        tsum += clip_len(u0x, u0y,  re0x,  re0y, hx1, hy1);
        tsum += clip_len(u1x, u1y,  re1x,  re1y, hx1, hy1);
        tsum += clip_len(u2x, u2y, -re0x, -re0y, hx1, hy1);
        tsum += clip_len(u3x, u3y, -re1x, -re1y, hx1, hy1);
        inter2 += 2.f * hx2 * hy2 * tsum;
    }

    float inter = 0.5f * fabsf(inter2);
    float areaU = w1v * l1v + w2v * l2v - inter;
    float iou = __fdividef(inter, areaU + EPSF);
    float giou = iou - __fdividef(enc - areaU, enc + EPSF);
    gout = 1.f - giou;
}

// 1 box/thread, maximum TLP, no occupancy cap, no masking in the common
// (exact-fit) case: shortest possible per-wave serial chain.
__global__ __launch_bounds__(BLOCK) void box_loss_main(
    const float* __restrict__ box, const float* __restrict__ tgt,
    const float* __restrict__ wgt, int n, float* __restrict__ partials)
{
    __shared__ float red[8];

    const int tid = threadIdx.x;
    const int i = blockIdx.x * BLOCK + tid;

    float sumL1 = 0.f, sumG = 0.f;
    if (i < n) {
        Row9 R = load_row(box, tgt, wgt, (size_t)i * 11);
        box_compute(R, sumL1, sumG);
    }

    // ---- block reduction (wave=64) ----
#pragma unroll
    for (int off = 32; off > 0; off >>= 1) {
        sumL1 += __shfl_down(sumL1, off);
        sumG  += __shfl_down(sumG, off);
    }
    const int wave = tid >> 6, lane = tid & 63;
    if (lane == 0) { red[wave] = sumL1; red[4 + wave] = sumG; }
    __syncthreads();
    if (tid == 0) {
        partials[2 * (size_t)blockIdx.x]     = red[0] + red[1] + red[2] + red[3];
        partials[2 * (size_t)blockIdx.x + 1] = red[4] + red[5] + red[6] + red[7];
    }
}

// Deterministic final reduction of per-block partials + 1/af scaling.
__global__ __launch_bounds__(256) void box_loss_final(
    const float* __restrict__ partials, int nblk,
    const int* __restrict__ avg_factor, float* __restrict__ out)
{
    __shared__ float red[8];
    float a = 0.f, g = 0.f;
    for (int i = threadIdx.x; i < nblk; i += 256) {
        a += partials[2 * (size_t)i];
        g += partials[2 * (size_t)i + 1];
    }
#pragma unroll
    for (int off = 32; off > 0; off >>= 1) {
        a += __shfl_down(a, off);
        g += __shfl_down(g, off);
    }
    const int wave = threadIdx.x >> 6, lane = threadIdx.x & 63;
    if (lane == 0) { red[wave] = a; red[4 + wave] = g; }
    __syncthreads();
    if (threadIdx.x == 0) {
        float af = (float)(*avg_factor);
        if (af < 1.f) af = 1.f;
        out[0] = (red[0] + red[1] + red[2] + red[3]) / af;
        out[1] = (red[4] + red[5] + red[6] + red[7]) / af;
    }
}

extern "C" void kernel_launch(void* const* d_in, const int* in_sizes, int n_in,
                              void* d_out, int out_size, void* d_ws, size_t ws_size,
                              hipStream_t stream) {
    const float* box = (const float*)d_in[0];
    const float* tgt = (const float*)d_in[1];
    const float* wgt = (const float*)d_in[2];
    const int*   af  = (const int*)d_in[3];
    float* out = (float*)d_out;
    float* partials = (float*)d_ws;

    int n = in_sizes[0] / 11;
    int nblk = (n + BLOCK - 1) / BLOCK;   // 2048 for N=524288 (exact fit)
    if (nblk < 1) nblk = 1;

    hipLaunchKernelGGL(box_loss_main, dim3(nblk), dim3(BLOCK), 0, stream,
                       box, tgt, wgt, n, partials);
    hipLaunchKernelGGL(box_loss_final, dim3(1), dim3(256), 0, stream,
                       partials, nblk, af, out);
}

// Round 18
// 19.244 us; speedup vs baseline: 1.0839x; 1.0839x over previous
//
#include <hip/hip_runtime.h>

#define BLOCK 256
#define ITERS 2
#define EPSF 1e-8f

// 16-byte vector load with only 4-byte alignment guarantee (rows are 44 B).
typedef float f4u __attribute__((ext_vector_type(4), aligned(4)));

struct Row9 { f4u b0, b1, b2, t0, t1, t2, w0, w1, w2; };

__device__ __forceinline__ Row9 load_row(const float* __restrict__ box,
                                         const float* __restrict__ tgt,
                                         const float* __restrict__ wgt,
                                         size_t r) {
    Row9 R;
    R.b0 = *(const f4u*)(box + r); R.b1 = *(const f4u*)(box + r + 4); R.b2 = *(const f4u*)(box + r + 7);
    R.t0 = *(const f4u*)(tgt + r); R.t1 = *(const f4u*)(tgt + r + 4); R.t2 = *(const f4u*)(tgt + r + 7);
    R.w0 = *(const f4u*)(wgt + r); R.w1 = *(const f4u*)(wgt + r + 4); R.w2 = *(const f4u*)(wgt + r + 7);
    return R;
}

__device__ __forceinline__ float safe_rcp(float d) {
    float sd = (fabsf(d) > 1e-30f) ? d : copysignf(1e-30f, d);
    return __frcp_rn(sd);
}

// Clipped length of segment p + t*d, t in [0,1], vs |x|<=hx,|y|<=hy.
__device__ __forceinline__ float clip_len(float px, float py,
                                          float rdx, float rdy,
                                          float hx, float hy) {
    float t1x = (-hx - px) * rdx, t2x = (hx - px) * rdx;
    float t1y = (-hy - py) * rdy, t2y = (hy - py) * rdy;
    float tmin = fmaxf(fmaxf(fminf(t1x, t2x), fminf(t1y, t2y)), 0.f);
    float tmax = fminf(fminf(fmaxf(t1x, t2x), fmaxf(t1y, t2y)), 1.f);
    return fmaxf(tmax - tmin, 0.f);
}

__device__ __forceinline__ void box_compute(const Row9& R, float& l1out, float& gout)
{
    f4u b0 = R.b0, b1 = R.b1, b2 = R.b2;
    f4u t0 = R.t0, t1 = R.t1, t2 = R.t2;
    f4u w0 = R.w0, w1 = R.w1, w2 = R.w2;

    // ---- L1 loss over the 11 components ----
    float lb = 0.f;
    lb += fabsf(b0.x - t0.x) * w0.x;
    lb += fabsf(b0.y - t0.y) * w0.y;
    lb += fabsf(b0.z - t0.z) * w0.z;
    lb += fabsf(b0.w - t0.w) * w0.w;
    lb += fabsf(b1.x - t1.x) * w1.x;
    lb += fabsf(b1.y - t1.y) * w1.y;
    lb += fabsf(b1.z - t1.z) * w1.z;
    lb += fabsf(b1.w - t1.w) * w1.w;
    lb += fabsf(b2.y - t2.y) * w2.y;
    lb += fabsf(b2.z - t2.z) * w2.z;
    lb += fabsf(b2.w - t2.w) * w2.w;
    l1out = lb;

    // ---- decode: sin(atan2(s,c)) = s*rsqrt(s^2+c^2); exp via HW ----
    float cx1 = b0.x, cy1 = b0.y, cx2 = t0.x, cy2 = t0.y;
    float w1v = __expf(b0.w), l1v = __expf(b1.x);
    float w2v = __expf(t0.w), l2v = __expf(t1.x);
    float r1 = rsqrtf(fmaxf(b1.z * b1.z + b1.w * b1.w, 1e-30f));
    float s1 = b1.z * r1, c1 = b1.w * r1;
    float r2 = rsqrtf(fmaxf(t1.z * t1.z + t1.w * t1.w, 1e-30f));
    float s2 = t1.z * r2, c2 = t1.w * r2;

    float hx1 = 0.5f * w1v, hy1 = 0.5f * l1v;
    float hx2 = 0.5f * w2v, hy2 = 0.5f * l2v;

    // enclosing AABB (world frame), closed form
    float e1x = fabsf(hx1 * c1) + fabsf(hy1 * s1);
    float e1y = fabsf(hx1 * s1) + fabsf(hy1 * c1);
    float e2x = fabsf(hx2 * c2) + fabsf(hy2 * s2);
    float e2y = fabsf(hx2 * s2) + fabsf(hy2 * c2);
    float enc = (fmaxf(cx1 + e1x, cx2 + e2x) - fminf(cx1 - e1x, cx2 - e2x))
              * (fmaxf(cy1 + e1y, cy2 + e2y) - fminf(cy1 - e1y, cy2 - e2y));

    // rect1 pose in rect2's local frame (rect2 axis-aligned there)
    float dxw = cx1 - cx2, dyw = cy1 - cy2;
    float txl =  c2 * dxw + s2 * dyw;
    float tyl = -s2 * dxw + c2 * dyw;
    float cr_ = c1 * c2 + s1 * s2;     // cos(yaw1 - yaw2)
    float sr_ = s1 * c2 - c1 * s2;     // sin(yaw1 - yaw2)

    // rect1 corners in frame2 via shared products
    float ax_ = hx1 * cr_, ay_ = hx1 * sr_;
    float bx_ = hy1 * sr_, by_ = hy1 * cr_;
    float q0x = txl - ax_ + bx_, q0y = tyl - ay_ - by_;
    float q1x = txl + ax_ + bx_, q1y = tyl + ay_ - by_;
    float q2x = txl + ax_ - bx_, q2y = tyl + ay_ + by_;
    float q3x = txl - ax_ - bx_, q3y = tyl - ay_ + by_;

    // ---- Green's theorem: inter2 = sum over boundary segments of
    // (tb-ta)*cross(p,d), all crosses evaluated in frame2 ----
    float inter2 = 0.f;

    // Part 1: rect1 edges vs rect2's box; edges 2,3 antiparallel to 0,1.
    {
        float d01x = 2.f * ax_, d01y = 2.f * ay_;
        float d12x = -2.f * bx_, d12y = 2.f * by_;
        float r01x = safe_rcp(d01x), r01y = safe_rcp(d01y);
        float r12x = safe_rcp(d12x), r12y = safe_rcp(d12y);

        float L0 = clip_len(q0x, q0y,  r01x,  r01y, hx2, hy2);
        inter2 += L0 * (q0x * d01y - q0y * d01x);
        float L1 = clip_len(q1x, q1y,  r12x,  r12y, hx2, hy2);
        inter2 += L1 * (q1x * d12y - q1y * d12x);
        float L2 = clip_len(q2x, q2y, -r01x, -r01y, hx2, hy2);
        inter2 += L2 * (q2y * d01x - q2x * d01y);
        float L3 = clip_len(q3x, q3y, -r12x, -r12y, hx2, hy2);
        inter2 += L3 * (q3y * d12x - q3x * d12y);
    }

    // Part 2: rect2 edges vs rect1's box; cross(p,d) == 2*hx2*hy2.
    {
        float zx = -hx2 - txl, zy = -hy2 - tyl;
        float u0x =  cr_ * zx + sr_ * zy;
        float u0y = -sr_ * zx + cr_ * zy;
        float E0x =  2.f * hx2 * cr_, E0y = -2.f * hx2 * sr_;
        float E1x =  2.f * hy2 * sr_, E1y =  2.f * hy2 * cr_;
        float u1x = u0x + E0x, u1y = u0y + E0y;
        float u2x = u1x + E1x, u2y = u1y + E1y;
        float u3x = u0x + E1x, u3y = u0y + E1y;
        float re0x = safe_rcp(E0x), re0y = safe_rcp(E0y);
        float re1x = safe_rcp(E1x), re1y = safe_rcp(E1y);

        float tsum = 0.f;
        tsum += clip_len(u0x, u0y,  re0x,  re0y, hx1, hy1);
        tsum += clip_len(u1x, u1y,  re1x,  re1y, hx1, hy1);
        tsum += clip_len(u2x, u2y, -re0x, -re0y, hx1, hy1);
        tsum += clip_len(u3x, u3y, -re1x, -re1y, hx1, hy1);
        inter2 += 2.f * hx2 * hy2 * tsum;
    }

    float inter = 0.5f * fabsf(inter2);
    float areaU = w1v * l1v + w2v * l2v - inter;
    float iou = __fdividef(inter, areaU + EPSF);
    float giou = iou - __fdividef(enc - areaU, enc + EPSF);
    gout = 1.f - giou;
}

// Best-measured structure (R10/R16, 19.4 us total): rolling 2-box pipeline,
// ITERS boxes/thread, 4 blocks/CU cap, two-kernel deterministic reduction.
__global__ __launch_bounds__(BLOCK, 4) void box_loss_main(
    const float* __restrict__ box, const float* __restrict__ tgt,
    const float* __restrict__ wgt, int n, int T, float* __restrict__ partials)
{
    __shared__ float red[8];

    const int tid = threadIdx.x;
    int i = blockIdx.x * BLOCK + tid;
    float sumL1 = 0.f, sumG = 0.f;

    bool v = i < n;
    Row9 cur = load_row(box, tgt, wgt, (size_t)(v ? i : 0) * 11);

#pragma unroll
    for (int k = 0; k < ITERS; ++k) {
        int inext = i + T;
        bool vnext = false;
        Row9 nxt;
        if (k + 1 < ITERS) {
            vnext = inext < n;
            nxt = load_row(box, tgt, wgt, (size_t)(vnext ? inext : 0) * 11);
        }
        float l1, g;
        box_compute(cur, l1, g);
        sumL1 += v ? l1 : 0.f;
        sumG  += v ? g  : 0.f;
        if (k + 1 < ITERS) { cur = nxt; v = vnext; i = inext; }
    }

    // ---- block reduction (wave=64) ----
#pragma unroll
    for (int off = 32; off > 0; off >>= 1) {
        sumL1 += __shfl_down(sumL1, off);
        sumG  += __shfl_down(sumG, off);
    }
    const int wave = tid >> 6, lane = tid & 63;
    if (lane == 0) { red[wave] = sumL1; red[4 + wave] = sumG; }
    __syncthreads();
    if (tid == 0) {
        partials[2 * (size_t)blockIdx.x]     = red[0] + red[1] + red[2] + red[3];
        partials[2 * (size_t)blockIdx.x + 1] = red[4] + red[5] + red[6] + red[7];
    }
}

// Deterministic final reduction of per-block partials + 1/af scaling.
__global__ __launch_bounds__(256) void box_loss_final(
    const float* __restrict__ partials, int nblk,
    const int* __restrict__ avg_factor, float* __restrict__ out)
{
    __shared__ float red[8];
    float a = 0.f, g = 0.f;
    for (int i = threadIdx.x; i < nblk; i += 256) {
        a += partials[2 * (size_t)i];
        g += partials[2 * (size_t)i + 1];
    }
#pragma unroll
    for (int off = 32; off > 0; off >>= 1) {
        a += __shfl_down(a, off);
        g += __shfl_down(g, off);
    }
    const int wave = threadIdx.x >> 6, lane = threadIdx.x & 63;
    if (lane == 0) { red[wave] = a; red[4 + wave] = g; }
    __syncthreads();
    if (threadIdx.x == 0) {
        float af = (float)(*avg_factor);
        if (af < 1.f) af = 1.f;
        out[0] = (red[0] + red[1] + red[2] + red[3]) / af;
        out[1] = (red[4] + red[5] + red[6] + red[7]) / af;
    }
}

extern "C" void kernel_launch(void* const* d_in, const int* in_sizes, int n_in,
                              void* d_out, int out_size, void* d_ws, size_t ws_size,
                              hipStream_t stream) {
    const float* box = (const float*)d_in[0];
    const float* tgt = (const float*)d_in[1];
    const float* wgt = (const float*)d_in[2];
    const int*   af  = (const int*)d_in[3];
    float* out = (float*)d_out;
    float* partials = (float*)d_ws;

    int n = in_sizes[0] / 11;
    int nblk = (n + BLOCK * ITERS - 1) / (BLOCK * ITERS);   // 1024 for N=524288
    if (nblk < 1) nblk = 1;
    int T = nblk * BLOCK;   // thread handles i and i+T

    hipLaunchKernelGGL(box_loss_main, dim3(nblk), dim3(BLOCK), 0, stream,
                       box, tgt, wgt, n, T, partials);
    hipLaunchKernelGGL(box_loss_final, dim3(1), dim3(256), 0, stream,
                       partials, nblk, af, out);
}